// Round 3
// baseline (5541.909 us; speedup 1.0000x reference)
//
#include <hip/hip_runtime.h>
#include <hip/hip_bf16.h>
#include <stdint.h>

#define T_LEN 8192
#define LAYERS 30

typedef __attribute__((ext_vector_type(8))) short bfx8;
typedef __attribute__((ext_vector_type(4))) float fx4;
typedef __attribute__((ext_vector_type(4))) int ix4;

static __device__ __forceinline__ unsigned short f2bf(float f) {
    union { float fv; unsigned u; } v; v.fv = f;
    unsigned r = v.u + 0x7fffu + ((v.u >> 16) & 1u);
    return (unsigned short)(r >> 16);
}
static __device__ __forceinline__ unsigned pack2(float a, float b) {
    return (unsigned)f2bf(a) | ((unsigned)f2bf(b) << 16);
}

// ---------------------------------------------------------------------------
// Hierarchical grid barrier: bar[0..7] group counters (128 blocks each),
// bar[8] groups-done, bar[9] generation (monotonic). Zeroed by pack_weights_k.
// __syncthreads drains block stores to L2; tid0's release fence writes back
// local-XCD L2; spinner's acquire fence invalidates before re-reading.
// ---------------------------------------------------------------------------
static __device__ __forceinline__ void grid_barrier(unsigned* bar, int grp, unsigned target) {
    __syncthreads();
    if (threadIdx.x == 0) {
        __threadfence();
        unsigned a = __hip_atomic_fetch_add(&bar[grp], 1u, __ATOMIC_ACQ_REL, __HIP_MEMORY_SCOPE_AGENT);
        if (a == 127u) {
            unsigned g = __hip_atomic_fetch_add(&bar[8], 1u, __ATOMIC_ACQ_REL, __HIP_MEMORY_SCOPE_AGENT);
            if (g == 7u) {
                for (int i = 0; i < 9; i++)
                    __hip_atomic_store(&bar[i], 0u, __ATOMIC_RELAXED, __HIP_MEMORY_SCOPE_AGENT);
                __hip_atomic_store(&bar[9], target, __ATOMIC_RELEASE, __HIP_MEMORY_SCOPE_AGENT);
            }
        }
        while (__hip_atomic_load(&bar[9], __ATOMIC_RELAXED, __HIP_MEMORY_SCOPE_AGENT) < target)
            __builtin_amdgcn_s_sleep(2);
        __threadfence();
    }
    __syncthreads();
}

// ---------------------------------------------------------------------------
// Weight packing: fragment-linear bf16 (layout validated R0-R2).
// Per layer 88 frags x 1KB. kl = (lane>>4)*8 + j matches A-side loads.
// Also zeroes the barrier counters (stream-ordered before mega_k).
// ---------------------------------------------------------------------------
__global__ void pack_weights_k(const float* __restrict__ conv_w,
                               const float* __restrict__ aux_w,
                               const float* __restrict__ out_w,
                               unsigned short* __restrict__ wpack,
                               unsigned* __restrict__ bar) {
    if (blockIdx.x == 0 && threadIdx.x < 16) bar[threadIdx.x] = 0u;
    int tid = blockIdx.x * 256 + threadIdx.x;   // total 30*88*64 = 168960
    if (tid >= 168960) return;
    int lane = tid & 63;
    int f = (tid >> 6) % 88;
    int l = tid / (88 * 64);
    unsigned short vals[8];
#pragma unroll
    for (int j = 0; j < 8; j++) {
        int kl = ((lane >> 4) * 8) + j;
        float v;
        if (f < 72) {
            int ks = f >> 3, nf = f & 7;
            int g = nf * 16 + (lane & 15);
            if (ks < 6) {
                int tap = ks >> 1;
                int i = (ks & 1) * 32 + kl;
                v = conv_w[((l * 128 + g) * 64 + i) * 3 + tap];
            } else {
                int a = (ks - 6) * 32 + kl;
                v = (a < 80) ? aux_w[(l * 128 + g) * 80 + a] : 0.f;
            }
        } else {
            int fo = f - 72;
            int ks = fo >> 3, nf = fo & 7;
            int p = nf * 16 + (lane & 15);
            v = out_w[(l * 128 + p) * 64 + ks * 32 + kl];
        }
        vals[j] = f2bf(v);
    }
    unsigned* dst = (unsigned*)(wpack + (size_t)tid * 8);
    dst[0] = (unsigned)vals[0] | ((unsigned)vals[1] << 16);
    dst[1] = (unsigned)vals[2] | ((unsigned)vals[3] << 16);
    dst[2] = (unsigned)vals[4] | ((unsigned)vals[5] << 16);
    dst[3] = (unsigned)vals[6] | ((unsigned)vals[7] << 16);
}

// ---------------------------------------------------------------------------
// Persistent fused WaveNet: 1024 blocks (4/CU), each owns one (b, 64-t) tile
// for all 30 layers. Residual-x (waves 0-1) and skip (waves 2-3) resident in
// registers as f32 C-fragments. c-tile + mask persistent in LDS. Grid barrier
// between layers (xbf double-buffer handoff).
// LDS map (40,960 B total):
//   [0,27648)      transient: xtap[3][64][72]u16 | sg[64][68]f32 + z[64][72]u16@17408
//                  | o[64][68]f32 | final: s[64][68]f32 + w1s/b1s/w2s
//   [27648,40960)  ctile[64][104]u16 persistent, mask f32 in pad at short 96
// ---------------------------------------------------------------------------
__global__ __launch_bounds__(256, 4) void mega_k(
    const float* __restrict__ xin, const float* __restrict__ xmask,
    const float* __restrict__ c,
    const float* __restrict__ fw, const float* __restrict__ fb,
    const float* __restrict__ conv_b, const float* __restrict__ out_b,
    const float* __restrict__ lw1, const float* __restrict__ lb1,
    const float* __restrict__ lw2, const float* __restrict__ lb2,
    unsigned short* __restrict__ xbfA, unsigned short* __restrict__ xbfB,
    const unsigned short* __restrict__ wpack,
    unsigned* __restrict__ bar, float* __restrict__ out)
{
    __shared__ char smem[40960];
    unsigned short* xtap  = (unsigned short*)smem;             // [3][64][72] u16
    float*          sg_l  = (float*)smem;                      // [64][68] f32
    unsigned short* z_l   = (unsigned short*)(smem + 17408);   // [64][72] u16
    float*          o_l   = (float*)smem;                      // [64][68] f32
    unsigned short* ctile = (unsigned short*)(smem + 27648);   // [64][104] u16 persistent

    const int tid  = threadIdx.x;
    const int lane = tid & 63;
    const int wv   = tid >> 6;
    const int bid  = ((int)blockIdx.x & 7) * 128 + ((int)blockIdx.x >> 3); // XCD-chunked
    const int b    = bid >> 7;
    const int t0   = (bid & 127) << 6;
    const long rowbase = (long)b * T_LEN;
    const int klane = (lane >> 4) * 8;
    const int mrow  = lane & 15;
    const int trow  = (lane >> 4) * 4;
    const int grp   = (int)blockIdx.x >> 7;

    // ---------------- prologue ----------------
    // c tile (zero-padded aux cols: pad MUST be 0, garbage NaN x 0-weight = NaN)
    for (int idx = tid; idx < 6144; idx += 256) {
        int a = idx >> 6, t = idx & 63;
        float v = (a < 80) ? c[((size_t)b * 80 + a) * T_LEN + t0 + t] : 0.f;
        ctile[t * 104 + a] = f2bf(v);
    }
    if (tid < 64)
        *(float*)(ctile + tid * 104 + 96) = xmask[rowbase + t0 + tid];
    // first 1x1 conv -> xbfA (bf16) for everyone + resident f32 x fragments
    {
        int r = tid >> 2, q = tid & 3;
        float xs = xin[rowbase + t0 + r];
        unsigned pk[8];
#pragma unroll
        for (int k = 0; k < 4; k++) {
            int ch = q * 16 + k * 4;
            float4 w  = *(const float4*)(fw + ch);
            float4 bb = *(const float4*)(fb + ch);
            pk[k * 2]     = pack2(fmaf(w.x, xs, bb.x), fmaf(w.y, xs, bb.y));
            pk[k * 2 + 1] = pack2(fmaf(w.z, xs, bb.z), fmaf(w.w, xs, bb.w));
        }
        unsigned short* dst = xbfA + ((rowbase + t0 + r) << 6) + q * 16;
        *(ix4*)dst       = *(ix4*)&pk[0];
        *(ix4*)(dst + 8) = *(ix4*)&pk[4];
    }
    fx4 racc[4][2];   // waves 0-1: residual x master; waves 2-3: skip accumulator
    if (wv < 2) {
#pragma unroll
        for (int m = 0; m < 4; m++)
#pragma unroll
            for (int n = 0; n < 2; n++) {
                int col = wv * 32 + n * 16 + mrow;
                float w = fw[col], bb = fb[col];
#pragma unroll
                for (int r = 0; r < 4; r++)
                    racc[m][n][r] = fmaf(w, xin[rowbase + t0 + m * 16 + trow + r], bb);
            }
    } else {
#pragma unroll
        for (int m = 0; m < 4; m++)
#pragma unroll
            for (int n = 0; n < 2; n++)
                racc[m][n] = (fx4){0.f, 0.f, 0.f, 0.f};
    }

    unsigned gen = 1;
    grid_barrier(bar, grp, gen);

    // ---------------- layer loop ----------------
#pragma unroll 1
    for (int l = 0; l < LAYERS; l++) {
        const unsigned short* curb = (l & 1) ? xbfB : xbfA;
        unsigned short*       nxtb = (l & 1) ? xbfA : xbfB;
        const int d = 1 << (l % 10);
        const unsigned short* wl = wpack + (size_t)l * 45056;
        const bool last = (l == LAYERS - 1);

        // stage x taps (bf16)
        for (int idx = tid; idx < 1536; idx += 256) {
            int tap = idx >> 9, rem = idx & 511, row = rem >> 3, seg = rem & 7;
            int tg = t0 + row + (tap - 1) * d;
            ix4 v = {0, 0, 0, 0};
            if ((unsigned)tg < (unsigned)T_LEN)
                v = *(const ix4*)(curb + ((rowbase + tg) << 6) + seg * 8);
            *(ix4*)(xtap + (tap * 64 + row) * 72 + seg * 8) = v;
        }
        __syncthreads();                                        // (1) taps ready

        // H GEMM: K = 3*64 conv taps + 96 aux(padded)
        fx4 acc[4][2];
#pragma unroll
        for (int m = 0; m < 4; m++) {
            acc[m][0] = (fx4){0.f, 0.f, 0.f, 0.f};
            acc[m][1] = (fx4){0.f, 0.f, 0.f, 0.f};
        }
        for (int ks = 0; ks < 9; ks++) {
            const unsigned short* abase; int off, stride;
            if (ks < 6) { abase = xtap + (ks >> 1) * (64 * 72); off = (ks & 1) * 32; stride = 72; }
            else        { abase = ctile;                        off = (ks - 6) * 32; stride = 104; }
            bfx8 af[4];
#pragma unroll
            for (int m = 0; m < 4; m++)
                af[m] = *(const bfx8*)(abase + (m * 16 + mrow) * stride + off + klane);
            bfx8 bfr[2];
#pragma unroll
            for (int n = 0; n < 2; n++)
                bfr[n] = *(const bfx8*)(wl + (size_t)((ks * 8 + (wv * 2 + n)) * 64 + lane) * 8);
#pragma unroll
            for (int m = 0; m < 4; m++)
#pragma unroll
                for (int n = 0; n < 2; n++)
                    acc[m][n] = __builtin_amdgcn_mfma_f32_16x16x32_bf16(af[m], bfr[n], acc[m][n], 0, 0, 0);
        }
        __syncthreads();                                        // (2) xtap dead

        // gate, split by wave role
        {
            float cb0 = conv_b[l * 128 + wv * 32 + mrow];
            float cb1 = conv_b[l * 128 + wv * 32 + 16 + mrow];
            if (wv >= 2) {   // sigma(xb) -> sg_l (f32)
#pragma unroll
                for (int n = 0; n < 2; n++) {
                    int col = (wv - 2) * 32 + n * 16 + mrow;
                    float cb = n ? cb1 : cb0;
#pragma unroll
                    for (int m = 0; m < 4; m++)
#pragma unroll
                        for (int r = 0; r < 4; r++) {
                            float h = acc[m][n][r] + cb;
                            sg_l[(m * 16 + trow + r) * 68 + col] = 1.f / (1.f + __expf(-h));
                        }
                }
            } else {         // tanh(xa) in-register
#pragma unroll
                for (int n = 0; n < 2; n++) {
                    float cb = n ? cb1 : cb0;
#pragma unroll
                    for (int m = 0; m < 4; m++)
#pragma unroll
                        for (int r = 0; r < 4; r++) {
                            float h = acc[m][n][r] + cb;
                            float e2 = __expf(2.f * h);
                            acc[m][n][r] = 1.f - 2.f / (e2 + 1.f);
                        }
                }
            }
        }
        __syncthreads();                                        // (3) sg ready
        if (wv < 2) {        // z = tanh * sigma -> z_l (bf16)
#pragma unroll
            for (int n = 0; n < 2; n++) {
                int col = wv * 32 + n * 16 + mrow;
#pragma unroll
                for (int m = 0; m < 4; m++)
#pragma unroll
                    for (int r = 0; r < 4; r++) {
                        int t = m * 16 + trow + r;
                        z_l[t * 72 + col] = f2bf(acc[m][n][r] * sg_l[t * 68 + col]);
                    }
            }
        }
        __syncthreads();                                        // (4) z ready

        // O GEMM: K = 64 (acc reused)
#pragma unroll
        for (int m = 0; m < 4; m++) {
            acc[m][0] = (fx4){0.f, 0.f, 0.f, 0.f};
            acc[m][1] = (fx4){0.f, 0.f, 0.f, 0.f};
        }
        for (int ks = 0; ks < 2; ks++) {
            bfx8 af[4];
#pragma unroll
            for (int m = 0; m < 4; m++)
                af[m] = *(const bfx8*)(z_l + (m * 16 + mrow) * 72 + ks * 32 + klane);
            bfx8 bfr[2];
#pragma unroll
            for (int n = 0; n < 2; n++)
                bfr[n] = *(const bfx8*)(wl + (size_t)(((72 + ks * 8) + (wv * 2 + n)) * 64 + lane) * 8);
#pragma unroll
            for (int m = 0; m < 4; m++)
#pragma unroll
                for (int n = 0; n < 2; n++)
                    acc[m][n] = __builtin_amdgcn_mfma_f32_16x16x32_bf16(af[m], bfr[n], acc[m][n], 0, 0, 0);
        }

        // epilogue: resident register update (o_l disjoint from z_l -> no sync)
#pragma unroll
        for (int n = 0; n < 2; n++) {
            int p = wv * 32 + n * 16 + mrow;
            float ob = out_b[l * 128 + p];
#pragma unroll
            for (int m = 0; m < 4; m++)
#pragma unroll
                for (int r = 0; r < 4; r++) {
                    int t = m * 16 + trow + r;
                    float mk = *(const float*)(ctile + t * 104 + 96);
                    float val = (acc[m][n][r] + ob) * mk;
                    racc[m][n][r] += val;
                    if (!last && wv < 2) o_l[t * 68 + p] = racc[m][n][r];
                }
        }
        if (!last) {
            __syncthreads();                                    // (6) o_l ready
            // pack new x -> nxtb (coalesced bf16)
            {
                int r = tid >> 2, q = tid & 3;
                const float* src = o_l + r * 68 + q * 16;
                unsigned pk[8];
#pragma unroll
                for (int k = 0; k < 4; k++) {
                    float4 v = *(const float4*)(src + k * 4);
                    pk[k * 2]     = pack2(v.x, v.y);
                    pk[k * 2 + 1] = pack2(v.z, v.w);
                }
                unsigned short* dst = nxtb + ((rowbase + t0 + r) << 6) + q * 16;
                *(ix4*)dst       = *(ix4*)&pk[0];
                *(ix4*)(dst + 8) = *(ix4*)&pk[4];
            }
            gen++;
            grid_barrier(bar, grp, gen);
        }
    }

    // ---------------- fused last_conv ----------------
    __syncthreads();   // all waves past O-GEMM/mask reads before overlays
    float* s_lds = o_l;                      // [64][68] f32
    float* w1s = (float*)(smem + 17408);     // [j][o] transposed, 16KB
    float* b1s = (float*)(smem + 33792);
    float* w2s = (float*)(smem + 34048);
    if (wv >= 2) {
#pragma unroll
        for (int n = 0; n < 2; n++) {
            int col = (wv - 2) * 32 + n * 16 + mrow;
#pragma unroll
            for (int m = 0; m < 4; m++)
#pragma unroll
                for (int r = 0; r < 4; r++)
                    s_lds[(m * 16 + trow + r) * 68 + col] = racc[m][n][r];
        }
    }
    for (int i = tid; i < 4096; i += 256) {
        int o = i & 63, j = i >> 6;
        w1s[j * 64 + o] = lw1[o * 64 + j];
    }
    if (tid < 64) { b1s[tid] = lb1[tid]; w2s[tid] = lw2[tid]; }
    __syncthreads();
    {
        int t = tid >> 2, q = tid & 3;
        float accf[16];
#pragma unroll
        for (int oi = 0; oi < 16; oi++) accf[oi] = b1s[q * 16 + oi];
        for (int j = 0; j < 64; j++) {
            float s = fmaxf(s_lds[t * 68 + j], 0.f);
            const float* wr = w1s + j * 64 + q * 16;
#pragma unroll
            for (int oi = 0; oi < 16; oi++) accf[oi] = fmaf(wr[oi], s, accf[oi]);
        }
        float tot = 0.f;
#pragma unroll
        for (int oi = 0; oi < 16; oi++) tot = fmaf(w2s[q * 16 + oi], fmaxf(accf[oi], 0.f), tot);
        tot += __shfl_xor(tot, 1);
        tot += __shfl_xor(tot, 2);
        if (q == 0) out[rowbase + t0 + t] = tot + lb2[0];
    }
}

extern "C" void kernel_launch(void* const* d_in, const int* in_sizes, int n_in,
                              void* d_out, int out_size, void* d_ws, size_t ws_size,
                              hipStream_t stream) {
    const float* x       = (const float*)d_in[0];
    const float* xmask   = (const float*)d_in[1];
    const float* c       = (const float*)d_in[2];
    const float* first_w = (const float*)d_in[3];
    const float* first_b = (const float*)d_in[4];
    const float* conv_w  = (const float*)d_in[5];
    const float* conv_b  = (const float*)d_in[6];
    const float* aux_w   = (const float*)d_in[7];
    const float* out_w   = (const float*)d_in[8];
    const float* out_b   = (const float*)d_in[9];
    const float* lw1     = (const float*)d_in[10];
    const float* lb1     = (const float*)d_in[11];
    const float* lw2     = (const float*)d_in[12];
    const float* lb2     = (const float*)d_in[13];
    float* outp = (float*)d_out;

    char* ws = (char*)d_ws;
    unsigned short* xbfA  = (unsigned short*)(ws + 0);          //  8,388,608 B
    unsigned short* xbfB  = (unsigned short*)(ws + 8388608);    //  8,388,608 B
    unsigned short* wpack = (unsigned short*)(ws + 16777216);   //  2,703,360 B
    unsigned*       bar   = (unsigned*)(ws + 19480576);         //         64 B

    pack_weights_k<<<660, 256, 0, stream>>>(conv_w, aux_w, out_w, wpack, bar);

    void* args[] = {
        (void*)&x, (void*)&xmask, (void*)&c, (void*)&first_w, (void*)&first_b,
        (void*)&conv_b, (void*)&out_b, (void*)&lw1, (void*)&lb1, (void*)&lw2,
        (void*)&lb2, (void*)&xbfA, (void*)&xbfB, (void*)&wpack, (void*)&bar,
        (void*)&outp
    };
    hipError_t e = hipLaunchCooperativeKernel((const void*)mega_k, dim3(1024),
                                              dim3(256), args, 0, stream);
    if (e != hipSuccess) {
        (void)hipGetLastError();   // clear; fall back to plain launch
        mega_k<<<1024, 256, 0, stream>>>(x, xmask, c, first_w, first_b,
                                         conv_b, out_b, lw1, lb1, lw2, lb2,
                                         xbfA, xbfB, wpack, bar, outp);
    }
}

// Round 5
// 963.186 us; speedup vs baseline: 5.7537x; 5.7537x over previous
//
#include <hip/hip_runtime.h>
#include <hip/hip_bf16.h>
#include <stdint.h>

#define T_LEN 8192
#define LAYERS 30

typedef __attribute__((ext_vector_type(8))) short bfx8;
typedef __attribute__((ext_vector_type(4))) float fx4;
typedef __attribute__((ext_vector_type(4))) int ix4;

static __device__ __forceinline__ unsigned short f2bf(float f) {
    union { float fv; unsigned u; } v; v.fv = f;
    unsigned r = v.u + 0x7fffu + ((v.u >> 16) & 1u);
    return (unsigned short)(r >> 16);
}
static __device__ __forceinline__ unsigned pack2(float a, float b) {
    return (unsigned)f2bf(a) | ((unsigned)f2bf(b) << 16);
}

// ---------------------------------------------------------------------------
// Weight packing: fragment-linear bf16 (layout validated R0-R3).
// Per layer 88 frags x 1KB. kl = (lane>>4)*8 + j matches A-side loads.
// ---------------------------------------------------------------------------
__global__ void pack_weights_k(const float* __restrict__ conv_w,
                               const float* __restrict__ aux_w,
                               const float* __restrict__ out_w,
                               unsigned short* __restrict__ wpack) {
    int tid = blockIdx.x * 256 + threadIdx.x;   // total 30*88*64 = 168960
    int lane = tid & 63;
    int f = (tid >> 6) % 88;
    int l = tid / (88 * 64);
    unsigned short vals[8];
#pragma unroll
    for (int j = 0; j < 8; j++) {
        int kl = ((lane >> 4) * 8) + j;
        float v;
        if (f < 72) {
            int ks = f >> 3, nf = f & 7;
            int g = nf * 16 + (lane & 15);
            if (ks < 6) {
                int tap = ks >> 1;
                int i = (ks & 1) * 32 + kl;
                v = conv_w[((l * 128 + g) * 64 + i) * 3 + tap];
            } else {
                int a = (ks - 6) * 32 + kl;
                v = (a < 80) ? aux_w[(l * 128 + g) * 80 + a] : 0.f;
            }
        } else {
            int fo = f - 72;
            int ks = fo >> 3, nf = fo & 7;
            int p = nf * 16 + (lane & 15);
            v = out_w[(l * 128 + p) * 64 + ks * 32 + kl];
        }
        vals[j] = f2bf(v);
    }
    unsigned* dst = (unsigned*)(wpack + (size_t)tid * 8);
    dst[0] = (unsigned)vals[0] | ((unsigned)vals[1] << 16);
    dst[1] = (unsigned)vals[2] | ((unsigned)vals[3] << 16);
    dst[2] = (unsigned)vals[4] | ((unsigned)vals[5] << 16);
    dst[3] = (unsigned)vals[6] | ((unsigned)vals[7] << 16);
}

// c (B,80,T) f32 -> cbf (B,T,96) bf16 zero-padded
__global__ void prep_c_k(const float* __restrict__ c, unsigned short* __restrict__ cbf) {
    __shared__ float tile[80][65];
    int bid = blockIdx.x;                 // B * 128 tiles
    int b = bid >> 7;
    int t0 = (bid & 127) << 6;
    for (int idx = threadIdx.x; idx < 80 * 64; idx += 256) {
        int a = idx >> 6, tt = idx & 63;
        tile[a][tt] = c[((size_t)(b * 80 + a)) * T_LEN + t0 + tt];
    }
    __syncthreads();
    for (int idx = threadIdx.x; idx < 64 * 96; idx += 256) {
        int tt = idx / 96, a = idx % 96;
        float v = (a < 80) ? tile[a][tt] : 0.f;
        cbf[((size_t)(b * T_LEN + t0 + tt)) * 96 + a] = f2bf(v);
    }
}

// first 1x1 conv -> xf32 (B,T,64) + xbfA (B,T,64);  also zero skip (B,T,64) f32
__global__ void first_init_k(const float* __restrict__ x,
                             const float* __restrict__ fw, const float* __restrict__ fb,
                             float* __restrict__ xf32, unsigned short* __restrict__ xbf,
                             float* __restrict__ skip) {
    int vi = blockIdx.x * 256 + threadIdx.x;   // 2 * 1048576 total
    if (vi < 1048576) {
        int pos = vi >> 4;
        int rc = (vi & 15) * 4;
        float xs = x[pos];
        const float4 w = *(const float4*)(fw + rc);
        const float4 bb = *(const float4*)(fb + rc);
        float4 val = make_float4(w.x * xs + bb.x, w.y * xs + bb.y,
                                 w.z * xs + bb.z, w.w * xs + bb.w);
        *(float4*)(xf32 + (((size_t)pos) << 6) + rc) = val;
        unsigned* dst = (unsigned*)(xbf + (((size_t)pos) << 6) + rc);
        dst[0] = (unsigned)f2bf(val.x) | ((unsigned)f2bf(val.y) << 16);
        dst[1] = (unsigned)f2bf(val.z) | ((unsigned)f2bf(val.w) << 16);
    } else {
        int si = vi - 1048576;
        float4 z = make_float4(0.f, 0.f, 0.f, 0.f);
        *(float4*)(skip + (size_t)si * 4) = z;
    }
}

// ---------------------------------------------------------------------------
// Fused layer. 256 threads (4 waves), tile 64 t x 128 ch, wave w owns ch [32w,32w+32).
// LDS = 40960 B exactly -> 4 blocks/CU -> all 1024 blocks co-resident, 1 round.
// Phase layouts (time-multiplexed):
//   stage/H-GEMM: xtap[3][64][72]u16 @0 (27648 B) | ctile[64][104]u16 @27648 (13312 B)
//   gate:         sg[64][68]f32 @0 (17408 B)      | z[64][72]u16 @17408 (9216 B)
//   epilogue:     o[64][132]f32 @0 (33792 B)  -- overlays z_l => sync after O-GEMM
// Mask applied in drain (1 global load per thread). R4-bug fixed: o stride >=128.
// ---------------------------------------------------------------------------
__global__ __launch_bounds__(256, 4) void layer_k(
    const unsigned short* __restrict__ xbf_cur,
    unsigned short* __restrict__ xbf_next,
    float* __restrict__ xf32,
    float* __restrict__ skip,
    const unsigned short* __restrict__ cbf,
    const float* __restrict__ xmask,
    const unsigned short* __restrict__ wl,
    const float* __restrict__ conv_b_l,
    const float* __restrict__ out_b_l,
    int d)
{
    __shared__ char smem[40960];
    unsigned short* xtap  = (unsigned short*)smem;             // [3][64][72] u16
    float*          sg_l  = (float*)smem;                      // [64][68] f32
    unsigned short* z_l   = (unsigned short*)(smem + 17408);   // [64][72] u16
    float*          o_l   = (float*)smem;                      // [64][132] f32
    unsigned short* ctile = (unsigned short*)(smem + 27648);   // [64][104] u16

    const int tid = threadIdx.x;
    const int lane = tid & 63;
    const int wv = tid >> 6;
    int bid = (((int)blockIdx.x & 7) * 128) + ((int)blockIdx.x >> 3);  // XCD-chunked
    const int b = bid >> 7;
    const int t0 = (bid & 127) << 6;
    const long rowbase = (long)b * T_LEN;
    const int klane = (lane >> 4) * 8;
    const int mrow = lane & 15;
    const int trow = (lane >> 4) * 4;

    // ---------- stage: x taps, c tile ----------
    for (int idx = tid; idx < 1536; idx += 256) {
        int tap = idx >> 9, rem = idx & 511, row = rem >> 3, seg = rem & 7;
        int tg = t0 + row + (tap - 1) * d;
        ix4 v = {0, 0, 0, 0};
        if ((unsigned)tg < (unsigned)T_LEN)
            v = *(const ix4*)(xbf_cur + ((rowbase + tg) << 6) + seg * 8);
        *(ix4*)(xtap + (tap * 64 + row) * 72 + seg * 8) = v;
    }
    for (int idx = tid; idx < 768; idx += 256) {
        int row = idx / 12, seg = idx % 12;
        ix4 v = *(const ix4*)(cbf + (rowbase + t0 + row) * 96 + seg * 8);
        *(ix4*)(ctile + row * 104 + seg * 8) = v;
    }

    // H-GEMM B-fragment prefetch (global, independent of LDS staging): 2-deep
    bfx8 bq[2][2];
#pragma unroll
    for (int pk = 0; pk < 2; pk++)
#pragma unroll
        for (int n = 0; n < 2; n++)
            bq[pk][n] = *(const bfx8*)(wl + (size_t)((pk * 8 + wv * 2 + n) * 64 + lane) * 8);
    __syncthreads();                                           // (1) taps+c ready

    // ---------- H GEMM: K = 3*64 conv taps + 96 aux(padded) ----------
    fx4 acc[4][2];
#pragma unroll
    for (int m = 0; m < 4; m++) {
        acc[m][0] = (fx4){0.f, 0.f, 0.f, 0.f};
        acc[m][1] = (fx4){0.f, 0.f, 0.f, 0.f};
    }
#pragma unroll
    for (int ks = 0; ks < 9; ks++) {
        const unsigned short* abase; int off, stride;
        if (ks < 6) { abase = xtap + (ks >> 1) * (64 * 72); off = (ks & 1) * 32; stride = 72; }
        else        { abase = ctile;                        off = (ks - 6) * 32; stride = 104; }
        bfx8 af[4];
#pragma unroll
        for (int m = 0; m < 4; m++)
            af[m] = *(const bfx8*)(abase + (m * 16 + mrow) * stride + off + klane);
        bfx8 b0 = bq[ks & 1][0], b1 = bq[ks & 1][1];
        if (ks + 2 < 9) {
#pragma unroll
            for (int n = 0; n < 2; n++)
                bq[ks & 1][n] = *(const bfx8*)(wl + (size_t)(((ks + 2) * 8 + wv * 2 + n) * 64 + lane) * 8);
        }
#pragma unroll
        for (int m = 0; m < 4; m++) {
            acc[m][0] = __builtin_amdgcn_mfma_f32_16x16x32_bf16(af[m], b0, acc[m][0], 0, 0, 0);
            acc[m][1] = __builtin_amdgcn_mfma_f32_16x16x32_bf16(af[m], b1, acc[m][1], 0, 0, 0);
        }
    }
    __syncthreads();                                           // (2) xtap+ctile dead

    // ---------- split gate ----------
    {
        float cb0 = conv_b_l[wv * 32 + mrow];
        float cb1 = conv_b_l[wv * 32 + 16 + mrow];
        if (wv >= 2) {        // sigma(xb) -> sg_l f32  (ch 64..127)
#pragma unroll
            for (int n = 0; n < 2; n++) {
                int col = (wv - 2) * 32 + n * 16 + mrow;
                float cb = n ? cb1 : cb0;
#pragma unroll
                for (int m = 0; m < 4; m++)
#pragma unroll
                    for (int r = 0; r < 4; r++) {
                        float h = acc[m][n][r] + cb;
                        sg_l[(m * 16 + trow + r) * 68 + col] = 1.f / (1.f + __expf(-h));
                    }
            }
        } else {              // tanh(xa) in-register  (ch 0..63)
#pragma unroll
            for (int n = 0; n < 2; n++) {
                float cb = n ? cb1 : cb0;
#pragma unroll
                for (int m = 0; m < 4; m++)
#pragma unroll
                    for (int r = 0; r < 4; r++) {
                        float h = acc[m][n][r] + cb;
                        float e2 = __expf(2.f * h);
                        acc[m][n][r] = 1.f - 2.f / (e2 + 1.f);
                    }
            }
        }
    }
    __syncthreads();                                           // (3) sg ready

    // O-GEMM B-fragment prefetch (overlaps z-compute)
    bfx8 ob[2][2];
#pragma unroll
    for (int ks = 0; ks < 2; ks++)
#pragma unroll
        for (int n = 0; n < 2; n++)
            ob[ks][n] = *(const bfx8*)(wl + (size_t)(((72 + ks * 8) + (wv * 2 + n)) * 64 + lane) * 8);

    if (wv < 2) {             // z = tanh * sigma -> z_l bf16
#pragma unroll
        for (int n = 0; n < 2; n++) {
            int col = wv * 32 + n * 16 + mrow;
#pragma unroll
            for (int m = 0; m < 4; m++)
#pragma unroll
                for (int r = 0; r < 4; r++) {
                    int t = m * 16 + trow + r;
                    z_l[t * 72 + col] = f2bf(acc[m][n][r] * sg_l[t * 68 + col]);
                }
        }
    }
    __syncthreads();                                           // (4) z ready

    // ---------- O GEMM: K = 64 ----------
    fx4 acc2[4][2];
#pragma unroll
    for (int m = 0; m < 4; m++) {
        acc2[m][0] = (fx4){0.f, 0.f, 0.f, 0.f};
        acc2[m][1] = (fx4){0.f, 0.f, 0.f, 0.f};
    }
#pragma unroll
    for (int ks = 0; ks < 2; ks++) {
        bfx8 af[4];
#pragma unroll
        for (int m = 0; m < 4; m++)
            af[m] = *(const bfx8*)(z_l + (m * 16 + mrow) * 72 + ks * 32 + klane);
#pragma unroll
        for (int m = 0; m < 4; m++) {
            acc2[m][0] = __builtin_amdgcn_mfma_f32_16x16x32_bf16(af[m], ob[ks][0], acc2[m][0], 0, 0, 0);
            acc2[m][1] = __builtin_amdgcn_mfma_f32_16x16x32_bf16(af[m], ob[ks][1], acc2[m][1], 0, 0, 0);
        }
    }
    __syncthreads();                                           // (5) z consumed; o_l may overlay

    // ---------- epilogue: bias -> o_l[64][132] (mask applied in drain) ----------
#pragma unroll
    for (int n = 0; n < 2; n++) {
        int p = wv * 32 + n * 16 + mrow;
        float ob_ = out_b_l[p];
#pragma unroll
        for (int m = 0; m < 4; m++)
#pragma unroll
            for (int r = 0; r < 4; r++) {
                int t = m * 16 + trow + r;
                o_l[t * 132 + p] = acc2[m][n][r] + ob_;
            }
    }
    __syncthreads();                                           // (6) o ready

    {
        int t = tid >> 2;          // 64 rows x 4 threads
        int q = tid & 3;           // q 0-1: residual ch [32q,..); q 2-3: skip
        float mk = xmask[rowbase + t0 + t];
        const float* src = o_l + t * 132 + q * 32;
        long ro = (rowbase + t0 + t) << 6;
        if (q < 2) {
            float* xp = xf32 + ro + q * 32;
            unsigned short* bp = xbf_next + ro + q * 32;
            unsigned pk[16];
#pragma unroll
            for (int k = 0; k < 8; k++) {
                float4 o4 = *(const float4*)(src + k * 4);
                float4 xv = *(float4*)(xp + k * 4);
                xv.x = fmaf(o4.x, mk, xv.x); xv.y = fmaf(o4.y, mk, xv.y);
                xv.z = fmaf(o4.z, mk, xv.z); xv.w = fmaf(o4.w, mk, xv.w);
                *(float4*)(xp + k * 4) = xv;
                pk[k * 2]     = pack2(xv.x, xv.y);
                pk[k * 2 + 1] = pack2(xv.z, xv.w);
            }
#pragma unroll
            for (int k = 0; k < 4; k++)
                *(ix4*)(bp + k * 8) = *(const ix4*)(pk + k * 4);
        } else {
            float* sp = skip + ro + (q - 2) * 32;
#pragma unroll
            for (int k = 0; k < 8; k++) {
                float4 o4 = *(const float4*)(src + k * 4);
                float4 sv = *(float4*)(sp + k * 4);
                sv.x = fmaf(o4.x, mk, sv.x); sv.y = fmaf(o4.y, mk, sv.y);
                sv.z = fmaf(o4.z, mk, sv.z); sv.w = fmaf(o4.w, mk, sv.w);
                *(float4*)(sp + k * 4) = sv;
            }
        }
    }
}

// last_conv: relu -> 1x1(64x64) -> relu -> 1x1(1x64). w1 in LDS, row in regs.
__global__ __launch_bounds__(256) void final_k(
        const float* __restrict__ skip,
        const float* __restrict__ w1, const float* __restrict__ b1,
        const float* __restrict__ w2, const float* __restrict__ b2,
        float* __restrict__ out) {
    __shared__ float w1s[4096];
    __shared__ float b1s[64];
    __shared__ float w2s[64];
    for (int i = threadIdx.x; i < 4096; i += 256) w1s[i] = w1[i];
    if (threadIdx.x < 64) {
        b1s[threadIdx.x] = b1[threadIdx.x];
        w2s[threadIdx.x] = w2[threadIdx.x];
    }
    __syncthreads();

    int pos = blockIdx.x * 256 + threadIdx.x;   // 65536 total
    const float4* row = (const float4*)(skip + (size_t)pos * 64);
    float4 s[16];
#pragma unroll
    for (int j = 0; j < 16; j++) {
        float4 v = row[j];
        s[j] = make_float4(fmaxf(v.x, 0.f), fmaxf(v.y, 0.f),
                           fmaxf(v.z, 0.f), fmaxf(v.w, 0.f));
    }
    float total = b2[0];
    for (int o = 0; o < 64; o++) {
        const float4* wr = (const float4*)(w1s + o * 64);
        float d0 = 0.f, d1 = 0.f, d2 = 0.f, d3 = 0.f;
#pragma unroll
        for (int j = 0; j < 16; j++) {
            float4 w = wr[j];
            d0 = fmaf(w.x, s[j].x, d0);
            d1 = fmaf(w.y, s[j].y, d1);
            d2 = fmaf(w.z, s[j].z, d2);
            d3 = fmaf(w.w, s[j].w, d3);
        }
        float dot = (d0 + d1) + (d2 + d3) + b1s[o];
        total = fmaf(w2s[o], fmaxf(dot, 0.f), total);
    }
    out[pos] = total;
}

extern "C" void kernel_launch(void* const* d_in, const int* in_sizes, int n_in,
                              void* d_out, int out_size, void* d_ws, size_t ws_size,
                              hipStream_t stream) {
    const float* x       = (const float*)d_in[0];
    const float* xmask   = (const float*)d_in[1];
    const float* c       = (const float*)d_in[2];
    const float* first_w = (const float*)d_in[3];
    const float* first_b = (const float*)d_in[4];
    const float* conv_w  = (const float*)d_in[5];
    const float* conv_b  = (const float*)d_in[6];
    const float* aux_w   = (const float*)d_in[7];
    const float* out_w   = (const float*)d_in[8];
    const float* out_b   = (const float*)d_in[9];
    const float* lw1     = (const float*)d_in[10];
    const float* lb1     = (const float*)d_in[11];
    const float* lw2     = (const float*)d_in[12];
    const float* lb2     = (const float*)d_in[13];
    float* out = (float*)d_out;

    char* ws = (char*)d_ws;
    float*          xf32  = (float*)(ws + 0);                   // 16,777,216 B
    unsigned short* xbfA  = (unsigned short*)(ws + 16777216);   //  8,388,608 B
    unsigned short* xbfB  = (unsigned short*)(ws + 25165824);   //  8,388,608 B
    float*          skip  = (float*)(ws + 33554432);            // 16,777,216 B
    unsigned short* cbf   = (unsigned short*)(ws + 50331648);   // 12,582,912 B
    unsigned short* wpack = (unsigned short*)(ws + 62914560);   //  2,703,360 B

    pack_weights_k<<<660, 256, 0, stream>>>(conv_w, aux_w, out_w, wpack);
    prep_c_k<<<1024, 256, 0, stream>>>(c, cbf);
    first_init_k<<<8192, 256, 0, stream>>>(x, first_w, first_b, xf32, xbfA, skip);

    const unsigned short* cur = xbfA;
    unsigned short* nxt = xbfB;
    for (int l = 0; l < LAYERS; l++) {
        int d = 1 << (l % 10);
        layer_k<<<1024, 256, 0, stream>>>(cur, nxt, xf32, skip, cbf, xmask,
                                          wpack + (size_t)l * 45056,
                                          conv_b + l * 128, out_b + l * 128, d);
        const unsigned short* tmp = nxt;
        nxt = (unsigned short*)cur;
        cur = tmp;
    }
    final_k<<<256, 256, 0, stream>>>(skip, lw1, lb1, lw2, lb2, out);
}

// Round 6
// 795.121 us; speedup vs baseline: 6.9699x; 1.2114x over previous
//
#include <hip/hip_runtime.h>
#include <hip/hip_bf16.h>
#include <stdint.h>

#define T_LEN 8192
#define LAYERS 30

typedef __attribute__((ext_vector_type(8))) short bfx8;
typedef __attribute__((ext_vector_type(4))) float fx4;
typedef __attribute__((ext_vector_type(4))) int ix4;

static __device__ __forceinline__ unsigned short f2bf(float f) {
    union { float fv; unsigned u; } v; v.fv = f;
    unsigned r = v.u + 0x7fffu + ((v.u >> 16) & 1u);
    return (unsigned short)(r >> 16);
}
static __device__ __forceinline__ float bf2f(unsigned short u) {
    union { unsigned u; float f; } v; v.u = ((unsigned)u) << 16;
    return v.f;
}
static __device__ __forceinline__ unsigned pack2(float a, float b) {
    return (unsigned)f2bf(a) | ((unsigned)f2bf(b) << 16);
}

// ---------------------------------------------------------------------------
// Weight packing: fragment-linear bf16 (layout validated R0-R5).
// Per layer 88 frags x 1KB. kl = (lane>>4)*8 + j matches A-side loads.
// ---------------------------------------------------------------------------
__global__ void pack_weights_k(const float* __restrict__ conv_w,
                               const float* __restrict__ aux_w,
                               const float* __restrict__ out_w,
                               unsigned short* __restrict__ wpack) {
    int tid = blockIdx.x * 256 + threadIdx.x;   // total 30*88*64 = 168960
    int lane = tid & 63;
    int f = (tid >> 6) % 88;
    int l = tid / (88 * 64);
    unsigned short vals[8];
#pragma unroll
    for (int j = 0; j < 8; j++) {
        int kl = ((lane >> 4) * 8) + j;
        float v;
        if (f < 72) {
            int ks = f >> 3, nf = f & 7;
            int g = nf * 16 + (lane & 15);
            if (ks < 6) {
                int tap = ks >> 1;
                int i = (ks & 1) * 32 + kl;
                v = conv_w[((l * 128 + g) * 64 + i) * 3 + tap];
            } else {
                int a = (ks - 6) * 32 + kl;
                v = (a < 80) ? aux_w[(l * 128 + g) * 80 + a] : 0.f;
            }
        } else {
            int fo = f - 72;
            int ks = fo >> 3, nf = fo & 7;
            int p = nf * 16 + (lane & 15);
            v = out_w[(l * 128 + p) * 64 + ks * 32 + kl];
        }
        vals[j] = f2bf(v);
    }
    unsigned* dst = (unsigned*)(wpack + (size_t)tid * 8);
    dst[0] = (unsigned)vals[0] | ((unsigned)vals[1] << 16);
    dst[1] = (unsigned)vals[2] | ((unsigned)vals[3] << 16);
    dst[2] = (unsigned)vals[4] | ((unsigned)vals[5] << 16);
    dst[3] = (unsigned)vals[6] | ((unsigned)vals[7] << 16);
}

// c (B,80,T) f32 -> cbf (B,T,96) bf16 zero-padded
__global__ void prep_c_k(const float* __restrict__ c, unsigned short* __restrict__ cbf) {
    __shared__ float tile[80][65];
    int bid = blockIdx.x;                 // B * 128 tiles
    int b = bid >> 7;
    int t0 = (bid & 127) << 6;
    for (int idx = threadIdx.x; idx < 80 * 64; idx += 256) {
        int a = idx >> 6, tt = idx & 63;
        tile[a][tt] = c[((size_t)(b * 80 + a)) * T_LEN + t0 + tt];
    }
    __syncthreads();
    for (int idx = threadIdx.x; idx < 64 * 96; idx += 256) {
        int tt = idx / 96, a = idx % 96;
        float v = (a < 80) ? tile[a][tt] : 0.f;
        cbf[((size_t)(b * T_LEN + t0 + tt)) * 96 + a] = f2bf(v);
    }
}

// ---------------------------------------------------------------------------
// Fused layer, traffic-lean form (R6):
//  - x master f32 double-buffered (xsrc->xdst); NO bf16 x copy. Taps read f32,
//    converted to bf16 during staging. Center tap kept in 16 regs/thread ->
//    drain writes xdst with no read.
//  - skip accumulator bf16 (B,T,64), RMW (write-only when first=1).
//  - first=1: taps/center computed from raw input via first conv on the fly.
// 256 thr (4 waves), tile 64 t x 128 ch. LDS 40960 B -> 4 blocks/CU (R5-verified).
// Phase LDS overlays identical to R5 (xtap/ctile -> sg|z -> o[64][132]).
// ---------------------------------------------------------------------------
__global__ __launch_bounds__(256, 4) void layer_k(
    const float* __restrict__ xsrc,      // first? xin (B,1,T) : x f32 (B,T,64)
    float* __restrict__ xdst,            // x f32 (B,T,64)
    unsigned short* __restrict__ skipbf, // (B,T,64) bf16 running sum
    const unsigned short* __restrict__ cbf,
    const float* __restrict__ xmask,
    const float* __restrict__ fw, const float* __restrict__ fb,
    const unsigned short* __restrict__ wl,
    const float* __restrict__ conv_b_l,
    const float* __restrict__ out_b_l,
    int d, int first)
{
    __shared__ char smem[40960];
    unsigned short* xtap  = (unsigned short*)smem;             // [3][64][72] u16
    float*          sg_l  = (float*)smem;                      // [64][68] f32
    unsigned short* z_l   = (unsigned short*)(smem + 17408);   // [64][72] u16
    float*          o_l   = (float*)smem;                      // [64][132] f32
    unsigned short* ctile = (unsigned short*)(smem + 27648);   // [64][104] u16

    const int tid = threadIdx.x;
    const int lane = tid & 63;
    const int wv = tid >> 6;
    int bid = (((int)blockIdx.x & 7) * 128) + ((int)blockIdx.x >> 3);  // XCD-chunked
    const int b = bid >> 7;
    const int t0 = (bid & 127) << 6;
    const long rowbase = (long)b * T_LEN;
    const int klane = (lane >> 4) * 8;
    const int mrow = lane & 15;
    const int trow = (lane >> 4) * 4;
    const int tq_t = tid >> 2;     // drain/center row
    const int tq_q = tid & 3;      // drain/center 16-ch chunk

    // ---------- stage: center tap (f32 regs + bf16 LDS) ----------
    float xc[16];
    if (first) {
        float xs = xsrc[rowbase + t0 + tq_t];
#pragma unroll
        for (int k = 0; k < 16; k++)
            xc[k] = fmaf(fw[tq_q * 16 + k], xs, fb[tq_q * 16 + k]);
    } else {
        const float4* src = (const float4*)(xsrc + ((rowbase + t0 + tq_t) << 6) + tq_q * 16);
#pragma unroll
        for (int k = 0; k < 4; k++) {
            float4 v = src[k];
            xc[k * 4] = v.x; xc[k * 4 + 1] = v.y; xc[k * 4 + 2] = v.z; xc[k * 4 + 3] = v.w;
        }
    }
    {
        unsigned pk[8];
#pragma unroll
        for (int k = 0; k < 8; k++) pk[k] = pack2(xc[k * 2], xc[k * 2 + 1]);
        unsigned short* dst = xtap + (64 + tq_t) * 72 + tq_q * 16;
        *(ix4*)dst       = *(const ix4*)&pk[0];
        *(ix4*)(dst + 8) = *(const ix4*)&pk[4];
    }
    // ---------- stage: halo taps (f32 -> bf16) ----------
#pragma unroll
    for (int u = 0; u < 2; u++) {
        int idx = tid + u * 256;            // 512 units: 2 taps x 64 rows x 4 chunks
        int tp = idx >> 8;                  // 0: -d, 1: +d
        int rem = idx & 255;
        int row = rem >> 2, qq = rem & 3;
        int tg = t0 + row + (tp ? d : -d);
        float hv[16];
        if ((unsigned)tg < (unsigned)T_LEN) {
            if (first) {
                float xs = xsrc[rowbase + tg];
#pragma unroll
                for (int k = 0; k < 16; k++)
                    hv[k] = fmaf(fw[qq * 16 + k], xs, fb[qq * 16 + k]);
            } else {
                const float4* src = (const float4*)(xsrc + ((rowbase + tg) << 6) + qq * 16);
#pragma unroll
                for (int k = 0; k < 4; k++) {
                    float4 v = src[k];
                    hv[k * 4] = v.x; hv[k * 4 + 1] = v.y; hv[k * 4 + 2] = v.z; hv[k * 4 + 3] = v.w;
                }
            }
        } else {
#pragma unroll
            for (int k = 0; k < 16; k++) hv[k] = 0.f;   // same-padding zeros
        }
        unsigned pk[8];
#pragma unroll
        for (int k = 0; k < 8; k++) pk[k] = pack2(hv[k * 2], hv[k * 2 + 1]);
        unsigned short* dst = xtap + (tp * 128 + row) * 72 + qq * 16;
        *(ix4*)dst       = *(const ix4*)&pk[0];
        *(ix4*)(dst + 8) = *(const ix4*)&pk[4];
    }
    // ---------- stage: c tile ----------
    for (int idx = tid; idx < 768; idx += 256) {
        int row = idx / 12, seg = idx % 12;
        ix4 v = *(const ix4*)(cbf + (rowbase + t0 + row) * 96 + seg * 8);
        *(ix4*)(ctile + row * 104 + seg * 8) = v;
    }

    // H-GEMM B-fragment prefetch: 2-deep
    bfx8 bq[2][2];
#pragma unroll
    for (int pk = 0; pk < 2; pk++)
#pragma unroll
        for (int n = 0; n < 2; n++)
            bq[pk][n] = *(const bfx8*)(wl + (size_t)((pk * 8 + wv * 2 + n) * 64 + lane) * 8);
    __syncthreads();                                           // (1) taps+c ready

    // ---------- H GEMM: K = 3*64 conv taps + 96 aux(padded) ----------
    fx4 acc[4][2];
#pragma unroll
    for (int m = 0; m < 4; m++) {
        acc[m][0] = (fx4){0.f, 0.f, 0.f, 0.f};
        acc[m][1] = (fx4){0.f, 0.f, 0.f, 0.f};
    }
#pragma unroll
    for (int ks = 0; ks < 9; ks++) {
        const unsigned short* abase; int off, stride;
        if (ks < 6) { abase = xtap + (ks >> 1) * (64 * 72); off = (ks & 1) * 32; stride = 72; }
        else        { abase = ctile;                        off = (ks - 6) * 32; stride = 104; }
        bfx8 af[4];
#pragma unroll
        for (int m = 0; m < 4; m++)
            af[m] = *(const bfx8*)(abase + (m * 16 + mrow) * stride + off + klane);
        bfx8 b0 = bq[ks & 1][0], b1 = bq[ks & 1][1];
        if (ks + 2 < 9) {
#pragma unroll
            for (int n = 0; n < 2; n++)
                bq[ks & 1][n] = *(const bfx8*)(wl + (size_t)(((ks + 2) * 8 + wv * 2 + n) * 64 + lane) * 8);
        }
#pragma unroll
        for (int m = 0; m < 4; m++) {
            acc[m][0] = __builtin_amdgcn_mfma_f32_16x16x32_bf16(af[m], b0, acc[m][0], 0, 0, 0);
            acc[m][1] = __builtin_amdgcn_mfma_f32_16x16x32_bf16(af[m], b1, acc[m][1], 0, 0, 0);
        }
    }
    __syncthreads();                                           // (2) xtap+ctile dead

    // ---------- split gate ----------
    {
        float cb0 = conv_b_l[wv * 32 + mrow];
        float cb1 = conv_b_l[wv * 32 + 16 + mrow];
        if (wv >= 2) {        // sigma(xb) -> sg_l f32  (ch 64..127)
#pragma unroll
            for (int n = 0; n < 2; n++) {
                int col = (wv - 2) * 32 + n * 16 + mrow;
                float cb = n ? cb1 : cb0;
#pragma unroll
                for (int m = 0; m < 4; m++)
#pragma unroll
                    for (int r = 0; r < 4; r++) {
                        float h = acc[m][n][r] + cb;
                        sg_l[(m * 16 + trow + r) * 68 + col] = 1.f / (1.f + __expf(-h));
                    }
            }
        } else {              // tanh(xa) in-register  (ch 0..63)
#pragma unroll
            for (int n = 0; n < 2; n++) {
                float cb = n ? cb1 : cb0;
#pragma unroll
                for (int m = 0; m < 4; m++)
#pragma unroll
                    for (int r = 0; r < 4; r++) {
                        float h = acc[m][n][r] + cb;
                        float e2 = __expf(2.f * h);
                        acc[m][n][r] = 1.f - 2.f / (e2 + 1.f);
                    }
            }
        }
    }
    __syncthreads();                                           // (3) sg ready

    // O-GEMM B-fragment prefetch (overlaps z-compute)
    bfx8 ob[2][2];
#pragma unroll
    for (int ks = 0; ks < 2; ks++)
#pragma unroll
        for (int n = 0; n < 2; n++)
            ob[ks][n] = *(const bfx8*)(wl + (size_t)(((72 + ks * 8) + (wv * 2 + n)) * 64 + lane) * 8);

    if (wv < 2) {             // z = tanh * sigma -> z_l bf16
#pragma unroll
        for (int n = 0; n < 2; n++) {
            int col = wv * 32 + n * 16 + mrow;
#pragma unroll
            for (int m = 0; m < 4; m++)
#pragma unroll
                for (int r = 0; r < 4; r++) {
                    int t = m * 16 + trow + r;
                    z_l[t * 72 + col] = f2bf(acc[m][n][r] * sg_l[t * 68 + col]);
                }
        }
    }
    __syncthreads();                                           // (4) z ready

    // ---------- O GEMM: K = 64 ----------
    fx4 acc2[4][2];
#pragma unroll
    for (int m = 0; m < 4; m++) {
        acc2[m][0] = (fx4){0.f, 0.f, 0.f, 0.f};
        acc2[m][1] = (fx4){0.f, 0.f, 0.f, 0.f};
    }
#pragma unroll
    for (int ks = 0; ks < 2; ks++) {
        bfx8 af[4];
#pragma unroll
        for (int m = 0; m < 4; m++)
            af[m] = *(const bfx8*)(z_l + (m * 16 + mrow) * 72 + ks * 32 + klane);
#pragma unroll
        for (int m = 0; m < 4; m++) {
            acc2[m][0] = __builtin_amdgcn_mfma_f32_16x16x32_bf16(af[m], ob[ks][0], acc2[m][0], 0, 0, 0);
            acc2[m][1] = __builtin_amdgcn_mfma_f32_16x16x32_bf16(af[m], ob[ks][1], acc2[m][1], 0, 0, 0);
        }
    }
    __syncthreads();                                           // (5) z consumed; o_l may overlay

    // ---------- epilogue: bias -> o_l[64][132] ----------
#pragma unroll
    for (int n = 0; n < 2; n++) {
        int p = wv * 32 + n * 16 + mrow;
        float ob_ = out_b_l[p];
#pragma unroll
        for (int m = 0; m < 4; m++)
#pragma unroll
            for (int r = 0; r < 4; r++) {
                int t = m * 16 + trow + r;
                o_l[t * 132 + p] = acc2[m][n][r] + ob_;
            }
    }
    __syncthreads();                                           // (6) o ready

    // ---------- drain: residual from regs (write-only x), skip bf16 RMW ----------
    {
        float mk = xmask[rowbase + t0 + tq_t];
        long ro = (rowbase + t0 + tq_t) << 6;
        const float* osrc = o_l + tq_t * 132;
        // residual ch [16q, 16q+16)
        float* xp = xdst + ro + tq_q * 16;
#pragma unroll
        for (int k2 = 0; k2 < 4; k2++) {
            float4 o4 = *(const float4*)(osrc + tq_q * 16 + k2 * 4);
            float4 xv;
            xv.x = fmaf(o4.x, mk, xc[k2 * 4 + 0]);
            xv.y = fmaf(o4.y, mk, xc[k2 * 4 + 1]);
            xv.z = fmaf(o4.z, mk, xc[k2 * 4 + 2]);
            xv.w = fmaf(o4.w, mk, xc[k2 * 4 + 3]);
            *(float4*)(xp + k2 * 4) = xv;
        }
        // skip ch 64+[16q, 16q+16), bf16 running sum
        unsigned short* sp = skipbf + ro + tq_q * 16;
        float sv[16];
        if (first) {
#pragma unroll
            for (int k = 0; k < 16; k++)
                sv[k] = osrc[64 + tq_q * 16 + k] * mk;
        } else {
            ix4 old0 = *(const ix4*)sp;
            ix4 old1 = *(const ix4*)(sp + 8);
            const unsigned short* op = (const unsigned short*)&old0;
            const unsigned short* op1 = (const unsigned short*)&old1;
#pragma unroll
            for (int k = 0; k < 8; k++)
                sv[k] = fmaf(osrc[64 + tq_q * 16 + k], mk, bf2f(op[k]));
#pragma unroll
            for (int k = 0; k < 8; k++)
                sv[8 + k] = fmaf(osrc[64 + tq_q * 16 + 8 + k], mk, bf2f(op1[k]));
        }
        unsigned pk[8];
#pragma unroll
        for (int k = 0; k < 8; k++) pk[k] = pack2(sv[k * 2], sv[k * 2 + 1]);
        *(ix4*)sp       = *(const ix4*)&pk[0];
        *(ix4*)(sp + 8) = *(const ix4*)&pk[4];
    }
}

// last_conv: relu -> 1x1(64x64) -> relu -> 1x1(1x64). skip read as bf16.
__global__ __launch_bounds__(256) void final_k(
        const unsigned short* __restrict__ skipbf,
        const float* __restrict__ w1, const float* __restrict__ b1,
        const float* __restrict__ w2, const float* __restrict__ b2,
        float* __restrict__ out) {
    __shared__ float w1s[4096];
    __shared__ float b1s[64];
    __shared__ float w2s[64];
    for (int i = threadIdx.x; i < 4096; i += 256) w1s[i] = w1[i];
    if (threadIdx.x < 64) {
        b1s[threadIdx.x] = b1[threadIdx.x];
        w2s[threadIdx.x] = w2[threadIdx.x];
    }
    __syncthreads();

    int pos = blockIdx.x * 256 + threadIdx.x;   // 65536 total
    const ix4* rowp = (const ix4*)(skipbf + (size_t)pos * 64);
    float4 s[16];
#pragma unroll
    for (int j = 0; j < 8; j++) {
        ix4 v = rowp[j];
        const unsigned short* pv = (const unsigned short*)&v;
        s[j * 2]     = make_float4(fmaxf(bf2f(pv[0]), 0.f), fmaxf(bf2f(pv[1]), 0.f),
                                   fmaxf(bf2f(pv[2]), 0.f), fmaxf(bf2f(pv[3]), 0.f));
        s[j * 2 + 1] = make_float4(fmaxf(bf2f(pv[4]), 0.f), fmaxf(bf2f(pv[5]), 0.f),
                                   fmaxf(bf2f(pv[6]), 0.f), fmaxf(bf2f(pv[7]), 0.f));
    }
    float total = b2[0];
    for (int o = 0; o < 64; o++) {
        const float4* wr = (const float4*)(w1s + o * 64);
        float d0 = 0.f, d1 = 0.f, d2 = 0.f, d3 = 0.f;
#pragma unroll
        for (int j = 0; j < 16; j++) {
            float4 w = wr[j];
            d0 = fmaf(w.x, s[j].x, d0);
            d1 = fmaf(w.y, s[j].y, d1);
            d2 = fmaf(w.z, s[j].z, d2);
            d3 = fmaf(w.w, s[j].w, d3);
        }
        float dot = (d0 + d1) + (d2 + d3) + b1s[o];
        total = fmaf(w2s[o], fmaxf(dot, 0.f), total);
    }
    out[pos] = total;
}

extern "C" void kernel_launch(void* const* d_in, const int* in_sizes, int n_in,
                              void* d_out, int out_size, void* d_ws, size_t ws_size,
                              hipStream_t stream) {
    const float* x       = (const float*)d_in[0];
    const float* xmask   = (const float*)d_in[1];
    const float* c       = (const float*)d_in[2];
    const float* first_w = (const float*)d_in[3];
    const float* first_b = (const float*)d_in[4];
    const float* conv_w  = (const float*)d_in[5];
    const float* conv_b  = (const float*)d_in[6];
    const float* aux_w   = (const float*)d_in[7];
    const float* out_w   = (const float*)d_in[8];
    const float* out_b   = (const float*)d_in[9];
    const float* lw1     = (const float*)d_in[10];
    const float* lb1     = (const float*)d_in[11];
    const float* lw2     = (const float*)d_in[12];
    const float* lb2     = (const float*)d_in[13];
    float* out = (float*)d_out;

    char* ws = (char*)d_ws;
    float*          xfA    = (float*)(ws + 0);                   // 16,777,216 B
    float*          xfB    = (float*)(ws + 16777216);            // 16,777,216 B
    unsigned short* skipbf = (unsigned short*)(ws + 33554432);   //  8,388,608 B
    unsigned short* cbf    = (unsigned short*)(ws + 41943040);   // 12,582,912 B
    unsigned short* wpack  = (unsigned short*)(ws + 54525952);   //  2,703,360 B (end 57.2 MB)

    pack_weights_k<<<660, 256, 0, stream>>>(conv_w, aux_w, out_w, wpack);
    prep_c_k<<<1024, 256, 0, stream>>>(c, cbf);

    const float* src = x;
    for (int l = 0; l < LAYERS; l++) {
        int d = 1 << (l % 10);
        float* dst = (l & 1) ? xfB : xfA;
        layer_k<<<1024, 256, 0, stream>>>(src, dst, skipbf, cbf, xmask,
                                          first_w, first_b,
                                          wpack + (size_t)l * 45056,
                                          conv_b + l * 128, out_b + l * 128,
                                          d, (l == 0) ? 1 : 0);
        src = dst;
    }
    final_k<<<256, 256, 0, stream>>>(skipbf, lw1, lb1, lw2, lb2, out);
}